// Round 2
// baseline (124.342 us; speedup 1.0000x reference)
//
#include <hip/hip_runtime.h>
#include <math.h>

// Problem constants (SCDM_89318139888190)
#define Bdim 8
#define Fdim 256
#define Tdim 32
#define Ddim 1024
#define NEGV (-1e30f)
#define TANH_SCALE 2.8853900817779268f   // 2*log2(e): tanh(x)=1-2*rcp(exp2(c*x)+1)
#define LOG2E 1.4426950408889634f

typedef unsigned short ushort;
using short8  = __attribute__((ext_vector_type(8))) short;   // 8 bf16 in 4 VGPRs
using floatx4 = __attribute__((ext_vector_type(4))) float;   // MFMA accumulator

__device__ __forceinline__ float fexp2(float x) { return __builtin_amdgcn_exp2f(x); }
__device__ __forceinline__ float frcp(float x)  { return __builtin_amdgcn_rcpf(x); }

__device__ __forceinline__ float fast_tanh(float x) {
    return 1.0f - 2.0f * frcp(fexp2(x * TANH_SCALE) + 1.0f);
}

__device__ __forceinline__ ushort f2bf(float f) {
    unsigned u = __float_as_uint(f);
    unsigned r = u + 0x7FFFu + ((u >> 16) & 1u);
    return (ushort)(r >> 16);
}

// async global->LDS, 16B per lane; LDS dst = base + lane*16 (wave-uniform base)
#define GLOAD_LDS16(gp, lp) __builtin_amdgcn_global_load_lds(                   \
    (const __attribute__((address_space(1))) void*)(gp),                        \
    (__attribute__((address_space(3))) void*)(lp), 16, 0, 0)

// gfx9 s_waitcnt immediate: vmcnt[3:0]=bits3:0, expcnt=bits6:4, lgkmcnt=bits11:8,
// vmcnt[5:4]=bits15:14. Leave expcnt/lgkmcnt unconstrained (max).
#define WAIT_VMCNT(n) __builtin_amdgcn_s_waitcnt(((n) & 0xF) | (7 << 4) | (15 << 8) | (((n) >> 4) << 14))

// ---------------------------------------------------------------------------
// prep (merged): blocks [0,2304) cast feat/txt rows to bf16;
// blocks [2304, 2304+2048) transpose+cast W / Ws 32x32 tiles.
// ---------------------------------------------------------------------------
__global__ __launch_bounds__(256) void prep(
    const float* __restrict__ feat, const float* __restrict__ txt,
    const float* __restrict__ W, const float* __restrict__ Ws,
    ushort* __restrict__ featB, ushort* __restrict__ txtB,
    ushort* __restrict__ WtB, ushort* __restrict__ WstB)
{
    __shared__ ushort tile[32][33];
    const int blk = blockIdx.x;
    const int NCAST = Bdim * Fdim + Bdim * Tdim;   // 2304
    if (blk < NCAST) {
        const float* in; ushort* out; int base;
        if (blk < Bdim * Fdim) { in = feat; out = featB; base = blk * Ddim; }
        else { in = txt; out = txtB; base = (blk - Bdim * Fdim) * Ddim; }
        const int i = base + threadIdx.x * 4;
        float4 v = *(const float4*)(in + i);
        ushort4 o;
        o.x = f2bf(v.x); o.y = f2bf(v.y); o.z = f2bf(v.z); o.w = f2bf(v.w);
        *(ushort4*)(out + i) = o;
    } else {
        int t = blk - NCAST;                      // 0..2047
        const float* in = (t < 1024) ? W : Ws;
        ushort* out = (t < 1024) ? WtB : WstB;
        t &= 1023;
        const int bx = (t & 31) * 32;             // col (n) base
        const int by = (t >> 5) * 32;             // row (k) base
        const int tx = threadIdx.x & 31;
        const int tg = threadIdx.x >> 5;
        #pragma unroll
        for (int r = tg; r < 32; r += 8)
            tile[r][tx] = f2bf(in[(size_t)(by + r) * Ddim + bx + tx]);
        __syncthreads();
        #pragma unroll
        for (int r = tg; r < 32; r += 8)
            out[(size_t)(bx + r) * Ddim + by + tx] = tile[tx][r];
    }
}

// ---------------------------------------------------------------------------
// bf16 MFMA GEMM v3: BM=128, BN=64, BK=32, 256 threads, EXPLICIT LDS
// double-buffer with raw s_barrier + manual vmcnt — prefetch loads stay in
// flight across the barrier (no vmcnt(0) drain).
// Epilogue stores exp2(c*(acc+bias)): exp(a+b)=exp(a)exp(b) lets attn phase 1
// form the 67M-element exponential as a product of two small precomputed
// factors (one trans op per inner element instead of two).
// ---------------------------------------------------------------------------
#define GBM 128
#define GBN 64
#define GBK 32

__global__ __launch_bounds__(256) void gemm_dual(
    const ushort* __restrict__ A1, const ushort* __restrict__ Bt1, float* __restrict__ C1,
    const ushort* __restrict__ A2, const ushort* __restrict__ Bt2, float* __restrict__ C2,
    const float* __restrict__ bias2)
{
    const int K = Ddim, N = Ddim;
    const int by = blockIdx.y;
    const ushort* A; const ushort* Bt; float* C; const float* bias; int m0;
    if (by < 16) { A = A1; Bt = Bt1; C = C1; bias = nullptr; m0 = by * GBM; }
    else         { A = A2; Bt = Bt2; C = C2; bias = bias2;  m0 = (by - 16) * GBM; }
    const int n0 = blockIdx.x * GBN;

    __shared__ __align__(16) ushort As[2][GBM * GBK];   // 2 x 8 KB
    __shared__ __align__(16) ushort Bs[2][GBN * GBK];   // 2 x 4 KB

    const int tid  = threadIdx.x;
    const int l    = tid & 63;
    const int wave = tid >> 6;

    const int wm = (wave >> 1) * 64;
    const int wn = (wave & 1) * 32;

    floatx4 acc[4][2];
    #pragma unroll
    for (int i = 0; i < 4; ++i)
        #pragma unroll
        for (int j = 0; j < 2; ++j)
            acc[i][j] = (floatx4){0.0f, 0.0f, 0.0f, 0.0f};

    const int lm = l & 15;
    const int lk = (l >> 4) * 8;

    const int crow = l >> 2;          // staging row within 16-row chunk
    const int ccol = (l & 3) * 8;     // staging k (ushort)

    const ushort* aSrc0 = A  + (size_t)(m0 + wave * 16       + crow) * K + ccol;
    const ushort* aSrc1 = A  + (size_t)(m0 + (wave + 4) * 16 + crow) * K + ccol;
    const ushort* bSrc  = Bt + (size_t)(n0 + wave * 16       + crow) * K + ccol;
    const int aOff0 = (wave * 16) * GBK;        // + lane*16B implicit in gload_lds
    const int aOff1 = ((wave + 4) * 16) * GBK;
    const int bOff  = (wave * 16) * GBK;

    const int NK = K / GBK;   // 32

    // prologue: tile 0 -> buf 0
    GLOAD_LDS16(aSrc0, &As[0][aOff0]);
    GLOAD_LDS16(aSrc1, &As[0][aOff1]);
    GLOAD_LDS16(bSrc,  &Bs[0][bOff]);

    for (int i = 0; i < NK; ++i) {
        const int cur = i & 1;
        if (i + 1 < NK) {
            const int kn = (i + 1) * GBK;
            const int nxt = cur ^ 1;
            GLOAD_LDS16(aSrc0 + kn, &As[nxt][aOff0]);
            GLOAD_LDS16(aSrc1 + kn, &As[nxt][aOff1]);
            GLOAD_LDS16(bSrc  + kn, &Bs[nxt][bOff]);
            WAIT_VMCNT(3);     // tile i's 3 loads retired; tile i+1 in flight
        } else {
            WAIT_VMCNT(0);
        }
        __builtin_amdgcn_s_barrier();   // tile i visible to all waves

        short8 af0 = *(const short8*)&As[cur][(wm +  0 + lm) * GBK + lk];
        short8 af1 = *(const short8*)&As[cur][(wm + 16 + lm) * GBK + lk];
        short8 af2 = *(const short8*)&As[cur][(wm + 32 + lm) * GBK + lk];
        short8 af3 = *(const short8*)&As[cur][(wm + 48 + lm) * GBK + lk];
        short8 bf0 = *(const short8*)&Bs[cur][(wn +  0 + lm) * GBK + lk];
        short8 bf1 = *(const short8*)&Bs[cur][(wn + 16 + lm) * GBK + lk];
        acc[0][0] = __builtin_amdgcn_mfma_f32_16x16x32_bf16(af0, bf0, acc[0][0], 0, 0, 0);
        acc[0][1] = __builtin_amdgcn_mfma_f32_16x16x32_bf16(af0, bf1, acc[0][1], 0, 0, 0);
        acc[1][0] = __builtin_amdgcn_mfma_f32_16x16x32_bf16(af1, bf0, acc[1][0], 0, 0, 0);
        acc[1][1] = __builtin_amdgcn_mfma_f32_16x16x32_bf16(af1, bf1, acc[1][1], 0, 0, 0);
        acc[2][0] = __builtin_amdgcn_mfma_f32_16x16x32_bf16(af2, bf0, acc[2][0], 0, 0, 0);
        acc[2][1] = __builtin_amdgcn_mfma_f32_16x16x32_bf16(af2, bf1, acc[2][1], 0, 0, 0);
        acc[3][0] = __builtin_amdgcn_mfma_f32_16x16x32_bf16(af3, bf0, acc[3][0], 0, 0, 0);
        acc[3][1] = __builtin_amdgcn_mfma_f32_16x16x32_bf16(af3, bf1, acc[3][1], 0, 0, 0);

        __builtin_amdgcn_s_barrier();   // all readers of buf[cur] done
    }

    const int rowq = (l >> 4) * 4;
    #pragma unroll
    for (int im = 0; im < 4; ++im) {
        #pragma unroll
        for (int in_ = 0; in_ < 2; ++in_) {
            const int col = n0 + wn + in_ * 16 + lm;
            float badd = (bias != nullptr) ? bias[col] : 0.0f;
            #pragma unroll
            for (int r = 0; r < 4; ++r) {
                const int row = m0 + wm + im * 16 + rowq + r;
                // exp2-transformed projection factor (see header comment)
                C[(size_t)row * N + col] = fexp2((acc[im][in_][r] + badd) * TANH_SCALE);
            }
        }
    }
}

// ---------------------------------------------------------------------------
// attn v7: NF=4 (512 blocks). Halves the per-f amortized L2 re-read of the
// tp_s panel (phase 1) and the txt panel (phase 2): 268 MB -> 134 MB grid
// total. Per-element math identical to v6 (mul+add+rcp+fma, 1 trans op).
// part[] is written directly per tt (no register spool) to keep VGPR <= 170;
// __launch_bounds__(256,3) => 3 blocks/CU, 12 waves/CU — enough for L2-bound.
// ---------------------------------------------------------------------------
__global__ __launch_bounds__(256, 3) void attn_fused(
    const float* __restrict__ feat,   // [B,F,D] raw
    const float* __restrict__ txt,    // [B,T,D] raw
    const int*   __restrict__ qmask,  // [B,T]
    const float* __restrict__ fp_s,   // [B*F,D]  exp2(c*feat_proj)
    const float* __restrict__ tp_s,   // [B*T,D]  exp2(c*(txt_proj+b))
    const float* __restrict__ wvec,   // [D]
    const float* __restrict__ Wcw,    // [D]
    const float* __restrict__ bcw,    // [1]
    const float* __restrict__ Wcb,    // [D]
    const float* __restrict__ bcb,    // [1]
    float* __restrict__ out)          // [B,F,D]
{
    const int blk  = blockIdx.x;          // 0..511
    const int f0   = blk * 4;
    const int b    = f0 >> 8;
    const int tid  = threadIdx.x;
    const int lane = tid & 63;
    const int wave = tid >> 6;

    __shared__ float part[4][Tdim][68];   // ~34.8 KB; stride 68: 2-way banks on write (free)
    __shared__ float srho[4][Tdim];
    __shared__ float satt[4][Tdim];
    __shared__ float sred[4][8];

    float4 wv[4], fv[4][4];
    const float* frb = fp_s + (size_t)f0 * Ddim;
    #pragma unroll
    for (int it = 0; it < 4; ++it) {
        const int d = lane * 4 + it * 256;
        wv[it] = *(const float4*)&wvec[d];
        #pragma unroll
        for (int r = 0; r < 4; ++r)
            fv[r][it] = *(const float4*)&frb[(size_t)r * Ddim + d];
    }
    float sumw = 0.0f;
    #pragma unroll
    for (int it = 0; it < 4; ++it)
        sumw += wv[it].x + wv[it].y + wv[it].z + wv[it].w;
    #pragma unroll
    for (int off = 32; off; off >>= 1) sumw += __shfl_xor(sumw, off, 64);

    // ---- phase 1: partial logits for 4 f rows, register double-buffered tp ----
    const float* tpb = tp_s + (size_t)b * Tdim * Ddim;
    float4 cur[4], nxt[4];
    {
        const float* tr = tpb + (size_t)(wave * 8) * Ddim;
        #pragma unroll
        for (int it = 0; it < 4; ++it)
            cur[it] = *(const float4*)&tr[lane * 4 + it * 256];
    }
    #pragma unroll
    for (int tt = 0; tt < 8; ++tt) {
        if (tt < 7) {
            const float* trn = tpb + (size_t)(wave * 8 + tt + 1) * Ddim;
            #pragma unroll
            for (int it = 0; it < 4; ++it)
                nxt[it] = *(const float4*)&trn[lane * 4 + it * 256];
        }
        float a[4] = {0.0f, 0.0f, 0.0f, 0.0f};
        #pragma unroll
        for (int it = 0; it < 4; ++it) {
            const float4 tv  = cur[it];
            const float4 wvi = wv[it];
            #pragma unroll
            for (int r = 0; r < 4; ++r) {
                const float4 fvi = fv[r][it];
                float e, rc;
                e = tv.x * fvi.x; rc = frcp(e + 1.0f); a[r] = fmaf(wvi.x, rc, a[r]);
                e = tv.y * fvi.y; rc = frcp(e + 1.0f); a[r] = fmaf(wvi.y, rc, a[r]);
                e = tv.z * fvi.z; rc = frcp(e + 1.0f); a[r] = fmaf(wvi.z, rc, a[r]);
                e = tv.w * fvi.w; rc = frcp(e + 1.0f); a[r] = fmaf(wvi.w, rc, a[r]);
            }
        }
        const int trow = wave * 8 + tt;
        part[0][trow][lane] = a[0];
        part[1][trow][lane] = a[1];
        part[2][trow][lane] = a[2];
        part[3][trow][lane] = a[3];
        #pragma unroll
        for (int it = 0; it < 4; ++it) cur[it] = nxt[it];
    }
    __syncthreads();

    // ---- deferred reduction: 2 threads per (f,t) pair (128 pairs) ----
    {
        const int pair = tid >> 1, q = tid & 1;
        const int f = pair >> 5, t = pair & 31;
        const float* src = &part[f][t][q * 32];
        float sum = 0.0f;
        #pragma unroll
        for (int j = 0; j < 8; ++j) {
            float4 v = *(const float4*)(src + j * 4);
            sum += ((v.x + v.y) + (v.z + v.w));
        }
        sum += __shfl_xor(sum, 1, 64);
        if (q == 0) srho[f][t] = sum;
    }
    __syncthreads();

    // ---- softmax: waves 0-1, 32 lanes per f-row (4 rows) ----
    if (wave < 2) {
        const int f = wave * 2 + (lane >> 5);
        const int t = lane & 31;
        const float q = (float)qmask[b * Tdim + t];
        float L = sumw - 2.0f * srho[f][t] + (1.0f - q) * NEGV;
        float m = L;
        #pragma unroll
        for (int off = 16; off; off >>= 1) m = fmaxf(m, __shfl_xor(m, off, 64));
        float e = fexp2((L - m) * LOG2E);
        float ssum = e;
        #pragma unroll
        for (int off = 16; off; off >>= 1) ssum += __shfl_xor(ssum, off, 64);
        satt[f][t] = e * frcp(ssum);
    }
    __syncthreads();

    // ---- phase 2: txt_h for 4 f rows; thread owns d0 = tid*4 ----
    const float* txtb = txt + (size_t)b * Tdim * Ddim;
    const int d0 = tid * 4;
    float4 th[4];
    #pragma unroll
    for (int r = 0; r < 4; ++r) th[r] = (float4){0.0f, 0.0f, 0.0f, 0.0f};
    #pragma unroll 8
    for (int t = 0; t < Tdim; ++t) {
        float4 tv = *(const float4*)&txtb[(size_t)t * Ddim + d0];
        #pragma unroll
        for (int r = 0; r < 4; ++r) {
            const float ar = satt[r][t];
            th[r].x = fmaf(ar, tv.x, th[r].x);
            th[r].y = fmaf(ar, tv.y, th[r].y);
            th[r].z = fmaf(ar, tv.z, th[r].z);
            th[r].w = fmaf(ar, tv.w, th[r].w);
        }
    }

    float4 wcw = *(const float4*)&Wcw[d0];
    float4 wcb = *(const float4*)&Wcb[d0];
    float pw[4], pb[4];
    #pragma unroll
    for (int r = 0; r < 4; ++r) {
        pw[r] = th[r].x*wcw.x + th[r].y*wcw.y + th[r].z*wcw.z + th[r].w*wcw.w;
        pb[r] = th[r].x*wcb.x + th[r].y*wcb.y + th[r].z*wcb.z + th[r].w*wcb.w;
    }
    #pragma unroll
    for (int off = 32; off; off >>= 1) {
        #pragma unroll
        for (int r = 0; r < 4; ++r) {
            pw[r] += __shfl_xor(pw[r], off, 64);
            pb[r] += __shfl_xor(pb[r], off, 64);
        }
    }
    if (lane == 0) {
        #pragma unroll
        for (int r = 0; r < 4; ++r) {
            sred[wave][r]     = pw[r];
            sred[wave][4 + r] = pb[r];
        }
    }
    __syncthreads();
    float ws[4], bs[4];
    #pragma unroll
    for (int r = 0; r < 4; ++r) {
        const float cw = sred[0][r] + sred[1][r] + sred[2][r] + sred[3][r];
        const float cb = sred[0][4+r] + sred[1][4+r] + sred[2][4+r] + sred[3][4+r];
        ws[r] = fast_tanh(cw + bcw[0]);
        bs[r] = fast_tanh(cb + bcb[0]);
    }

    const float* ft0 = feat + (size_t)f0 * Ddim;
    #pragma unroll
    for (int r = 0; r < 4; ++r) {
        float4 v = *(const float4*)&ft0[(size_t)r * Ddim + d0];
        float4 o;
        o.x = fmaf(ws[r], v.x, bs[r]);
        o.y = fmaf(ws[r], v.y, bs[r]);
        o.z = fmaf(ws[r], v.z, bs[r]);
        o.w = fmaf(ws[r], v.w, bs[r]);
        *(float4*)&out[(size_t)(f0 + r) * Ddim + d0] = o;
    }
}

// ---------------------------------------------------------------------------
extern "C" void kernel_launch(void* const* d_in, const int* in_sizes, int n_in,
                              void* d_out, int out_size, void* d_ws, size_t ws_size,
                              hipStream_t stream) {
    const float* features = (const float*)d_in[0];   // [B,F,D]
    const float* textual  = (const float*)d_in[2];   // [B,T,D]
    const int*   q_masks  = (const int*)d_in[3];     // [B,T]
    const float* Ws       = (const float*)d_in[4];   // [D,D]
    const float* W        = (const float*)d_in[5];   // [D,D]
    const float* wvec     = (const float*)d_in[6];   // [D,1]
    const float* bvec     = (const float*)d_in[7];   // [1,D]
    const float* Wcw      = (const float*)d_in[8];   // [1,D]
    const float* bcw      = (const float*)d_in[9];   // [1]
    const float* Wcb      = (const float*)d_in[10];  // [1,D]
    const float* bcb      = (const float*)d_in[11];  // [1]
    float* out = (float*)d_out;

    float*  fp_ws = (float*)d_ws;                          // 2048*1024 f32 (exp2-transformed)
    float*  tp_ws = fp_ws + (size_t)Bdim * Fdim * Ddim;    // 256*1024 f32 (exp2-transformed)
    ushort* featB = (ushort*)(tp_ws + (size_t)Bdim * Tdim * Ddim);
    ushort* txtB  = featB + (size_t)Bdim * Fdim * Ddim;
    ushort* WtB   = txtB + (size_t)Bdim * Tdim * Ddim;
    ushort* WstB  = WtB + (size_t)Ddim * Ddim;

    // 1. merged prep: cast activations + transpose/cast weights
    prep<<<Bdim * Fdim + Bdim * Tdim + 2048, 256, 0, stream>>>(
        features, textual, W, Ws, featB, txtB, WtB, WstB);
    // 2. both projections, one MFMA dispatch (explicit dbuf, raw barriers)
    gemm_dual<<<dim3(Ddim / GBN, 18), 256, 0, stream>>>(
        featB, WtB, fp_ws, txtB, WstB, tp_ws, bvec);
    // 3. fused attention + conditioning (NF=4, exp2-factored phase 1)
    attn_fused<<<(Bdim * Fdim) / 4, 256, 0, stream>>>(
        features, textual, q_masks, fp_ws, tp_ws,
        wvec, Wcw, bcw, Wcb, bcb, out);
}

// Round 3
// 122.243 us; speedup vs baseline: 1.0172x; 1.0172x over previous
//
#include <hip/hip_runtime.h>
#include <math.h>

// Problem constants (SCDM_89318139888190)
#define Bdim 8
#define Fdim 256
#define Tdim 32
#define Ddim 1024
#define NEGV (-1e30f)
#define TANH_SCALE 2.8853900817779268f   // 2*log2(e): tanh(x)=1-2*rcp(exp2(c*x)+1)
#define LOG2E 1.4426950408889634f

typedef unsigned short ushort;
using short8  = __attribute__((ext_vector_type(8))) short;   // 8 bf16 in 4 VGPRs
using floatx4 = __attribute__((ext_vector_type(4))) float;   // MFMA accumulator

__device__ __forceinline__ float fexp2(float x) { return __builtin_amdgcn_exp2f(x); }
__device__ __forceinline__ float frcp(float x)  { return __builtin_amdgcn_rcpf(x); }

__device__ __forceinline__ float fast_tanh(float x) {
    return 1.0f - 2.0f * frcp(fexp2(x * TANH_SCALE) + 1.0f);
}

__device__ __forceinline__ ushort f2bf(float f) {
    unsigned u = __float_as_uint(f);
    unsigned r = u + 0x7FFFu + ((u >> 16) & 1u);
    return (ushort)(r >> 16);
}

// async global->LDS, 16B per lane; LDS dst = base + lane*16 (wave-uniform base)
#define GLOAD_LDS16(gp, lp) __builtin_amdgcn_global_load_lds(                   \
    (const __attribute__((address_space(1))) void*)(gp),                        \
    (__attribute__((address_space(3))) void*)(lp), 16, 0, 0)

// gfx9 s_waitcnt immediate: vmcnt[3:0]=bits3:0, expcnt=bits6:4, lgkmcnt=bits11:8,
// vmcnt[5:4]=bits15:14. Leave expcnt/lgkmcnt unconstrained (max).
#define WAIT_VMCNT(n) __builtin_amdgcn_s_waitcnt(((n) & 0xF) | (7 << 4) | (15 << 8) | (((n) >> 4) << 14))

// ---------------------------------------------------------------------------
// prep (merged): blocks [0,2304) cast feat/txt rows to bf16;
// blocks [2304, 2304+2048) transpose+cast W / Ws 32x32 tiles.
// ---------------------------------------------------------------------------
__global__ __launch_bounds__(256) void prep(
    const float* __restrict__ feat, const float* __restrict__ txt,
    const float* __restrict__ W, const float* __restrict__ Ws,
    ushort* __restrict__ featB, ushort* __restrict__ txtB,
    ushort* __restrict__ WtB, ushort* __restrict__ WstB)
{
    __shared__ ushort tile[32][33];
    const int blk = blockIdx.x;
    const int NCAST = Bdim * Fdim + Bdim * Tdim;   // 2304
    if (blk < NCAST) {
        const float* in; ushort* out; int base;
        if (blk < Bdim * Fdim) { in = feat; out = featB; base = blk * Ddim; }
        else { in = txt; out = txtB; base = (blk - Bdim * Fdim) * Ddim; }
        const int i = base + threadIdx.x * 4;
        float4 v = *(const float4*)(in + i);
        ushort4 o;
        o.x = f2bf(v.x); o.y = f2bf(v.y); o.z = f2bf(v.z); o.w = f2bf(v.w);
        *(ushort4*)(out + i) = o;
    } else {
        int t = blk - NCAST;                      // 0..2047
        const float* in = (t < 1024) ? W : Ws;
        ushort* out = (t < 1024) ? WtB : WstB;
        t &= 1023;
        const int bx = (t & 31) * 32;             // col (n) base
        const int by = (t >> 5) * 32;             // row (k) base
        const int tx = threadIdx.x & 31;
        const int tg = threadIdx.x >> 5;
        #pragma unroll
        for (int r = tg; r < 32; r += 8)
            tile[r][tx] = f2bf(in[(size_t)(by + r) * Ddim + bx + tx]);
        __syncthreads();
        #pragma unroll
        for (int r = tg; r < 32; r += 8)
            out[(size_t)(bx + r) * Ddim + by + tx] = tile[tx][r];
    }
}

// ---------------------------------------------------------------------------
// bf16 MFMA GEMM v4: BM=128, BN=64, BK=32, **512 threads (8 waves)** =>
// 2 waves/SIMD for intra-tile latency hiding (v3's 256-thread blocks put
// exactly 1 wave/SIMD: all ds_read latency + barriers fully exposed).
// Explicit LDS double-buffer with raw s_barrier + manual per-wave vmcnt:
//   all 8 waves stage 16 A-rows each; waves 0-3 additionally stage 16 B-rows.
//   outstanding loads/tile: 2 (waves 0-3) or 1 (waves 4-7) -> wave-uniform
//   scalar branch selects the matching vmcnt immediate.
// Per wave: 32x32 output, acc[2][2], 4 MFMA + 4 ds_read_b128 per K-step.
// Epilogue stores exp2(c*(acc+bias)): exp(a+b)=exp(a)exp(b) lets attn phase 1
// form the 67M-element exponential as a product of two small precomputed
// factors (one trans op per inner element instead of two).
// ---------------------------------------------------------------------------
#define GBM 128
#define GBN 64
#define GBK 32

__global__ __launch_bounds__(512, 4) void gemm_dual(
    const ushort* __restrict__ A1, const ushort* __restrict__ Bt1, float* __restrict__ C1,
    const ushort* __restrict__ A2, const ushort* __restrict__ Bt2, float* __restrict__ C2,
    const float* __restrict__ bias2)
{
    const int K = Ddim, N = Ddim;
    const int by = blockIdx.y;
    const ushort* A; const ushort* Bt; float* C; const float* bias; int m0;
    if (by < 16) { A = A1; Bt = Bt1; C = C1; bias = nullptr; m0 = by * GBM; }
    else         { A = A2; Bt = Bt2; C = C2; bias = bias2;  m0 = (by - 16) * GBM; }
    const int n0 = blockIdx.x * GBN;

    __shared__ __align__(16) ushort As[2][GBM * GBK];   // 2 x 8 KB
    __shared__ __align__(16) ushort Bs[2][GBN * GBK];   // 2 x 4 KB

    const int tid  = threadIdx.x;
    const int l    = tid & 63;
    const int wave = tid >> 6;          // 0..7

    const int wm = (wave >> 1) * 32;    // 0,32,64,96
    const int wn = (wave & 1) * 32;     // 0,32

    floatx4 acc[2][2];
    #pragma unroll
    for (int i = 0; i < 2; ++i)
        #pragma unroll
        for (int j = 0; j < 2; ++j)
            acc[i][j] = (floatx4){0.0f, 0.0f, 0.0f, 0.0f};

    const int lm = l & 15;
    const int lk = (l >> 4) * 8;

    const int crow = l >> 2;          // staging row within 16-row chunk
    const int ccol = (l & 3) * 8;     // staging k (ushort)

    const ushort* aSrc = A  + (size_t)(m0 + wave * 16 + crow) * K + ccol;   // all 8 waves
    const ushort* bSrc = Bt + (size_t)(n0 + wave * 16 + crow) * K + ccol;   // waves 0-3 only
    const int aOff = (wave * 16) * GBK;        // + lane*16B implicit in gload_lds
    const int bOff = (wave * 16) * GBK;
    const bool doB = (wave < 4);

    const int NK = K / GBK;   // 32

    // prologue: tile 0 -> buf 0
    GLOAD_LDS16(aSrc, &As[0][aOff]);
    if (doB) GLOAD_LDS16(bSrc, &Bs[0][bOff]);

    for (int i = 0; i < NK; ++i) {
        const int cur = i & 1;
        if (i + 1 < NK) {
            const int kn = (i + 1) * GBK;
            const int nxt = cur ^ 1;
            GLOAD_LDS16(aSrc + kn, &As[nxt][aOff]);
            if (doB) {
                GLOAD_LDS16(bSrc + kn, &Bs[nxt][bOff]);
                WAIT_VMCNT(2);     // cur tile's A+B retired; next tile's 2 in flight
            } else {
                WAIT_VMCNT(1);     // cur tile's A retired; next tile's A in flight
            }
        } else {
            WAIT_VMCNT(0);
        }
        __builtin_amdgcn_s_barrier();   // tile i visible to all waves

        short8 af0 = *(const short8*)&As[cur][(wm +  0 + lm) * GBK + lk];
        short8 af1 = *(const short8*)&As[cur][(wm + 16 + lm) * GBK + lk];
        short8 bf0 = *(const short8*)&Bs[cur][(wn +  0 + lm) * GBK + lk];
        short8 bf1 = *(const short8*)&Bs[cur][(wn + 16 + lm) * GBK + lk];
        acc[0][0] = __builtin_amdgcn_mfma_f32_16x16x32_bf16(af0, bf0, acc[0][0], 0, 0, 0);
        acc[0][1] = __builtin_amdgcn_mfma_f32_16x16x32_bf16(af0, bf1, acc[0][1], 0, 0, 0);
        acc[1][0] = __builtin_amdgcn_mfma_f32_16x16x32_bf16(af1, bf0, acc[1][0], 0, 0, 0);
        acc[1][1] = __builtin_amdgcn_mfma_f32_16x16x32_bf16(af1, bf1, acc[1][1], 0, 0, 0);

        __builtin_amdgcn_s_barrier();   // all readers of buf[cur] done
    }

    const int rowq = (l >> 4) * 4;
    #pragma unroll
    for (int im = 0; im < 2; ++im) {
        #pragma unroll
        for (int in_ = 0; in_ < 2; ++in_) {
            const int col = n0 + wn + in_ * 16 + lm;
            float badd = (bias != nullptr) ? bias[col] : 0.0f;
            #pragma unroll
            for (int r = 0; r < 4; ++r) {
                const int row = m0 + wm + im * 16 + rowq + r;
                // exp2-transformed projection factor (see header comment)
                C[(size_t)row * N + col] = fexp2((acc[im][in_][r] + badd) * TANH_SCALE);
            }
        }
    }
}

// ---------------------------------------------------------------------------
// attn v6 (reverted from NF=4: phase 1 is trans/VALU-pipe bound, not L2-BW
// bound — NF=4's register pressure cost more than the traffic halving gained).
// NF=2, deferred reduction, register double-buffer prefetch.
// Phase-1 inner element is mul+add+rcp+fma (ONE trans op): the exp2 factors
// exp2(c*tp) / exp2(c*fp) arrive precomputed from the GEMM epilogue.
// tanh(x) = 1 - 2/(exp2(c*x)+1) with exp2(c*(tp+fp)) = tpe*fpe.
// ---------------------------------------------------------------------------
__global__ __launch_bounds__(256, 4) void attn_fused(
    const float* __restrict__ feat,   // [B,F,D] raw
    const float* __restrict__ txt,    // [B,T,D] raw
    const int*   __restrict__ qmask,  // [B,T]
    const float* __restrict__ fp_s,   // [B*F,D]  exp2(c*feat_proj)
    const float* __restrict__ tp_s,   // [B*T,D]  exp2(c*(txt_proj+b))
    const float* __restrict__ wvec,   // [D]
    const float* __restrict__ Wcw,    // [D]
    const float* __restrict__ bcw,    // [1]
    const float* __restrict__ Wcb,    // [D]
    const float* __restrict__ bcb,    // [1]
    float* __restrict__ out)          // [B,F,D]
{
    const int blk  = blockIdx.x;          // 0..1023
    const int f0   = blk * 2;
    const int b    = f0 >> 8;
    const int tid  = threadIdx.x;
    const int lane = tid & 63;
    const int wave = tid >> 6;

    __shared__ float part[2][Tdim][68];   // stride 68: 2-way banks (free)
    __shared__ float srho[2][Tdim];
    __shared__ float satt[2][Tdim];
    __shared__ float sred[4][4];

    float4 wv[4], fva[4], fvb[4];
    const float* fr0 = fp_s + (size_t)f0 * Ddim;
    const float* fr1 = fr0 + Ddim;
    #pragma unroll
    for (int it = 0; it < 4; ++it) {
        const int d = lane * 4 + it * 256;
        wv[it]  = *(const float4*)&wvec[d];
        fva[it] = *(const float4*)&fr0[d];
        fvb[it] = *(const float4*)&fr1[d];
    }
    float sumw = 0.0f;
    #pragma unroll
    for (int it = 0; it < 4; ++it)
        sumw += wv[it].x + wv[it].y + wv[it].z + wv[it].w;
    #pragma unroll
    for (int off = 32; off; off >>= 1) sumw += __shfl_xor(sumw, off, 64);

    // ---- phase 1: partial logits, register double-buffered tp loads ----
    const float* tpb = tp_s + (size_t)b * Tdim * Ddim;
    float s0[8], s1[8];
    float4 cur[4], nxt[4];
    {
        const float* tr = tpb + (size_t)(wave * 8) * Ddim;
        #pragma unroll
        for (int it = 0; it < 4; ++it)
            cur[it] = *(const float4*)&tr[lane * 4 + it * 256];
    }
    #pragma unroll
    for (int tt = 0; tt < 8; ++tt) {
        if (tt < 7) {
            const float* trn = tpb + (size_t)(wave * 8 + tt + 1) * Ddim;
            #pragma unroll
            for (int it = 0; it < 4; ++it)
                nxt[it] = *(const float4*)&trn[lane * 4 + it * 256];
        }
        float a0 = 0.0f, b0 = 0.0f, a1 = 0.0f, b1 = 0.0f;
        #pragma unroll
        for (int it = 0; it < 4; ++it) {
            float4 tv = cur[it];
            float e, r;
            e = tv.x * fva[it].x; r = frcp(e + 1.0f); a0 = fmaf(wv[it].x, r, a0);
            e = tv.y * fva[it].y; r = frcp(e + 1.0f); b0 = fmaf(wv[it].y, r, b0);
            e = tv.z * fva[it].z; r = frcp(e + 1.0f); a0 = fmaf(wv[it].z, r, a0);
            e = tv.w * fva[it].w; r = frcp(e + 1.0f); b0 = fmaf(wv[it].w, r, b0);
            e = tv.x * fvb[it].x; r = frcp(e + 1.0f); a1 = fmaf(wv[it].x, r, a1);
            e = tv.y * fvb[it].y; r = frcp(e + 1.0f); b1 = fmaf(wv[it].y, r, b1);
            e = tv.z * fvb[it].z; r = frcp(e + 1.0f); a1 = fmaf(wv[it].z, r, a1);
            e = tv.w * fvb[it].w; r = frcp(e + 1.0f); b1 = fmaf(wv[it].w, r, b1);
        }
        s0[tt] = a0 + b0;
        s1[tt] = a1 + b1;
        #pragma unroll
        for (int it = 0; it < 4; ++it) cur[it] = nxt[it];
    }
    #pragma unroll
    for (int tt = 0; tt < 8; ++tt) {
        part[0][wave * 8 + tt][lane] = s0[tt];
        part[1][wave * 8 + tt][lane] = s1[tt];
    }
    __syncthreads();

    // ---- deferred reduction: 4 threads per (f,t) pair ----
    {
        const int pair = tid >> 2, q = tid & 3;
        const int f = pair >> 5, t = pair & 31;
        const float* src = &part[f][t][q * 16];
        float4 v0 = *(const float4*)(src);
        float4 v1 = *(const float4*)(src + 4);
        float4 v2 = *(const float4*)(src + 8);
        float4 v3 = *(const float4*)(src + 12);
        float sum = ((v0.x + v0.y) + (v0.z + v0.w))
                  + ((v1.x + v1.y) + (v1.z + v1.w))
                  + ((v2.x + v2.y) + (v2.z + v2.w))
                  + ((v3.x + v3.y) + (v3.z + v3.w));
        sum += __shfl_xor(sum, 1, 64);
        sum += __shfl_xor(sum, 2, 64);
        if (q == 0) srho[f][t] = sum;
    }
    __syncthreads();

    // ---- softmax: wave 0, 32 lanes per f-row ----
    if (wave == 0) {
        const int f = lane >> 5, t = lane & 31;
        const float q = (float)qmask[b * Tdim + t];
        float L = sumw - 2.0f * srho[f][t] + (1.0f - q) * NEGV;
        float m = L;
        #pragma unroll
        for (int off = 16; off; off >>= 1) m = fmaxf(m, __shfl_xor(m, off, 64));
        float e = fexp2((L - m) * LOG2E);
        float ssum = e;
        #pragma unroll
        for (int off = 16; off; off >>= 1) ssum += __shfl_xor(ssum, off, 64);
        satt[f][t] = e * frcp(ssum);
    }
    __syncthreads();

    // ---- phase 2: txt_h for both f rows; thread owns d0 = tid*4 ----
    const float* txtb = txt + (size_t)b * Tdim * Ddim;
    const int d0 = tid * 4;
    float4 th0 = {0,0,0,0}, th1 = {0,0,0,0};
    #pragma unroll 8
    for (int t = 0; t < Tdim; ++t) {
        float4 tv = *(const float4*)&txtb[(size_t)t * Ddim + d0];
        const float a0 = satt[0][t], a1 = satt[1][t];
        th0.x = fmaf(a0, tv.x, th0.x); th0.y = fmaf(a0, tv.y, th0.y);
        th0.z = fmaf(a0, tv.z, th0.z); th0.w = fmaf(a0, tv.w, th0.w);
        th1.x = fmaf(a1, tv.x, th1.x); th1.y = fmaf(a1, tv.y, th1.y);
        th1.z = fmaf(a1, tv.z, th1.z); th1.w = fmaf(a1, tv.w, th1.w);
    }

    float4 wcw = *(const float4*)&Wcw[d0];
    float4 wcb = *(const float4*)&Wcb[d0];
    float p00 = th0.x*wcw.x + th0.y*wcw.y + th0.z*wcw.z + th0.w*wcw.w;
    float p01 = th0.x*wcb.x + th0.y*wcb.y + th0.z*wcb.z + th0.w*wcb.w;
    float p10 = th1.x*wcw.x + th1.y*wcw.y + th1.z*wcw.z + th1.w*wcw.w;
    float p11 = th1.x*wcb.x + th1.y*wcb.y + th1.z*wcb.z + th1.w*wcb.w;
    #pragma unroll
    for (int off = 32; off; off >>= 1) {
        p00 += __shfl_xor(p00, off, 64);
        p01 += __shfl_xor(p01, off, 64);
        p10 += __shfl_xor(p10, off, 64);
        p11 += __shfl_xor(p11, off, 64);
    }
    if (lane == 0) {
        sred[wave][0] = p00; sred[wave][1] = p01;
        sred[wave][2] = p10; sred[wave][3] = p11;
    }
    __syncthreads();
    const float c00 = sred[0][0] + sred[1][0] + sred[2][0] + sred[3][0];
    const float c01 = sred[0][1] + sred[1][1] + sred[2][1] + sred[3][1];
    const float c10 = sred[0][2] + sred[1][2] + sred[2][2] + sred[3][2];
    const float c11 = sred[0][3] + sred[1][3] + sred[2][3] + sred[3][3];
    const float ws0 = fast_tanh(c00 + bcw[0]);
    const float bs0 = fast_tanh(c01 + bcb[0]);
    const float ws1 = fast_tanh(c10 + bcw[0]);
    const float bs1 = fast_tanh(c11 + bcb[0]);

    const float* ft0 = feat + (size_t)f0 * Ddim;
    float4 v0 = *(const float4*)&ft0[d0];
    float4 v1 = *(const float4*)&ft0[Ddim + d0];
    float4 o0, o1;
    o0.x = fmaf(ws0, v0.x, bs0); o0.y = fmaf(ws0, v0.y, bs0);
    o0.z = fmaf(ws0, v0.z, bs0); o0.w = fmaf(ws0, v0.w, bs0);
    o1.x = fmaf(ws1, v1.x, bs1); o1.y = fmaf(ws1, v1.y, bs1);
    o1.z = fmaf(ws1, v1.z, bs1); o1.w = fmaf(ws1, v1.w, bs1);
    *(float4*)&out[(size_t)f0 * Ddim + d0] = o0;
    *(float4*)&out[(size_t)f0 * Ddim + Ddim + d0] = o1;
}

// ---------------------------------------------------------------------------
extern "C" void kernel_launch(void* const* d_in, const int* in_sizes, int n_in,
                              void* d_out, int out_size, void* d_ws, size_t ws_size,
                              hipStream_t stream) {
    const float* features = (const float*)d_in[0];   // [B,F,D]
    const float* textual  = (const float*)d_in[2];   // [B,T,D]
    const int*   q_masks  = (const int*)d_in[3];     // [B,T]
    const float* Ws       = (const float*)d_in[4];   // [D,D]
    const float* W        = (const float*)d_in[5];   // [D,D]
    const float* wvec     = (const float*)d_in[6];   // [D,1]
    const float* bvec     = (const float*)d_in[7];   // [1,D]
    const float* Wcw      = (const float*)d_in[8];   // [1,D]
    const float* bcw      = (const float*)d_in[9];   // [1]
    const float* Wcb      = (const float*)d_in[10];  // [1,D]
    const float* bcb      = (const float*)d_in[11];  // [1]
    float* out = (float*)d_out;

    float*  fp_ws = (float*)d_ws;                          // 2048*1024 f32 (exp2-transformed)
    float*  tp_ws = fp_ws + (size_t)Bdim * Fdim * Ddim;    // 256*1024 f32 (exp2-transformed)
    ushort* featB = (ushort*)(tp_ws + (size_t)Bdim * Tdim * Ddim);
    ushort* txtB  = featB + (size_t)Bdim * Fdim * Ddim;
    ushort* WtB   = txtB + (size_t)Bdim * Tdim * Ddim;
    ushort* WstB  = WtB + (size_t)Ddim * Ddim;

    // 1. merged prep: cast activations + transpose/cast weights
    prep<<<Bdim * Fdim + Bdim * Tdim + 2048, 256, 0, stream>>>(
        features, textual, W, Ws, featB, txtB, WtB, WstB);
    // 2. both projections, one MFMA dispatch (8-wave blocks, 2 waves/SIMD)
    gemm_dual<<<dim3(Ddim / GBN, 18), 512, 0, stream>>>(
        featB, WtB, fp_ws, txtB, WstB, tp_ws, bvec);
    // 3. fused attention + conditioning (NF=2, exp2-factored phase 1)
    attn_fused<<<(Bdim * Fdim) / 2, 256, 0, stream>>>(
        features, textual, q_masks, fp_ws, tp_ws,
        wvec, Wcw, bcw, Wcb, bcb, out);
}

// Round 4
// 120.476 us; speedup vs baseline: 1.0321x; 1.0147x over previous
//
#include <hip/hip_runtime.h>
#include <math.h>

// Problem constants (SCDM_89318139888190)
#define Bdim 8
#define Fdim 256
#define Tdim 32
#define Ddim 1024
#define NEGV (-1e30f)
#define TANH_SCALE 2.8853900817779268f   // 2*log2(e): tanh(x)=1-2*rcp(exp2(c*x)+1)
#define LOG2E 1.4426950408889634f

typedef unsigned short ushort;
using short8  = __attribute__((ext_vector_type(8))) short;   // 8 bf16 in 4 VGPRs
using floatx4 = __attribute__((ext_vector_type(4))) float;   // MFMA accumulator

__device__ __forceinline__ float fexp2(float x) { return __builtin_amdgcn_exp2f(x); }
__device__ __forceinline__ float frcp(float x)  { return __builtin_amdgcn_rcpf(x); }

__device__ __forceinline__ float fast_tanh(float x) {
    return 1.0f - 2.0f * frcp(fexp2(x * TANH_SCALE) + 1.0f);
}

__device__ __forceinline__ ushort f2bf(float f) {
    unsigned u = __float_as_uint(f);
    unsigned r = u + 0x7FFFu + ((u >> 16) & 1u);
    return (ushort)(r >> 16);
}

// async global->LDS, 16B per lane; LDS dst = base + lane*16 (wave-uniform base)
#define GLOAD_LDS16(gp, lp) __builtin_amdgcn_global_load_lds(                   \
    (const __attribute__((address_space(1))) void*)(gp),                        \
    (__attribute__((address_space(3))) void*)(lp), 16, 0, 0)

// gfx9 s_waitcnt immediate: vmcnt[3:0]=bits3:0, expcnt=bits6:4, lgkmcnt=bits11:8,
// vmcnt[5:4]=bits15:14. Leave expcnt/lgkmcnt unconstrained (max).
#define WAIT_VMCNT(n) __builtin_amdgcn_s_waitcnt(((n) & 0xF) | (7 << 4) | (15 << 8) | (((n) >> 4) << 14))

// ---------------------------------------------------------------------------
// prep (merged): blocks [0,2304) cast feat/txt rows to bf16;
// blocks [2304, 2304+2048) transpose+cast W / Ws 32x32 tiles.
// ---------------------------------------------------------------------------
__global__ __launch_bounds__(256) void prep(
    const float* __restrict__ feat, const float* __restrict__ txt,
    const float* __restrict__ W, const float* __restrict__ Ws,
    ushort* __restrict__ featB, ushort* __restrict__ txtB,
    ushort* __restrict__ WtB, ushort* __restrict__ WstB)
{
    __shared__ ushort tile[32][33];
    const int blk = blockIdx.x;
    const int NCAST = Bdim * Fdim + Bdim * Tdim;   // 2304
    if (blk < NCAST) {
        const float* in; ushort* out; int base;
        if (blk < Bdim * Fdim) { in = feat; out = featB; base = blk * Ddim; }
        else { in = txt; out = txtB; base = (blk - Bdim * Fdim) * Ddim; }
        const int i = base + threadIdx.x * 4;
        float4 v = *(const float4*)(in + i);
        ushort4 o;
        o.x = f2bf(v.x); o.y = f2bf(v.y); o.z = f2bf(v.z); o.w = f2bf(v.w);
        *(ushort4*)(out + i) = o;
    } else {
        int t = blk - NCAST;                      // 0..2047
        const float* in = (t < 1024) ? W : Ws;
        ushort* out = (t < 1024) ? WtB : WstB;
        t &= 1023;
        const int bx = (t & 31) * 32;             // col (n) base
        const int by = (t >> 5) * 32;             // row (k) base
        const int tx = threadIdx.x & 31;
        const int tg = threadIdx.x >> 5;
        #pragma unroll
        for (int r = tg; r < 32; r += 8)
            tile[r][tx] = f2bf(in[(size_t)(by + r) * Ddim + bx + tx]);
        __syncthreads();
        #pragma unroll
        for (int r = tg; r < 32; r += 8)
            out[(size_t)(bx + r) * Ddim + by + tx] = tile[tx][r];
    }
}

// ---------------------------------------------------------------------------
// bf16 MFMA GEMM v5: BM=128, **BN=128**, BK=32, 512 threads (8 waves).
// Grid shrinks 288 -> 144 blocks (<= 256 CUs): kills the 2-blocks-per-CU
// straggler tail of v4 (288 > 256 meant 32 CUs ran 2x the work = makespan 2x
// single-block time). Per wave: 32x128 output (acc 2x4) -> 6 ds_read_b128
// feed 8 MFMA per K-step (was 4:4), cutting the LDS-read-bound K-step ~25%.
// Explicit LDS double-buffer, raw s_barrier + manual vmcnt: every wave stages
// 16 A-rows + 16 B-rows per tile (2 outstanding loads -> uniform vmcnt(2)).
// Epilogue stores exp2(c*(acc+bias)): exp(a+b)=exp(a)exp(b) lets attn phase 1
// form the 67M-element exponential as a product of two small precomputed
// factors (one trans op per inner element pair instead of two).
// ---------------------------------------------------------------------------
#define GBM 128
#define GBN 128
#define GBK 32

__global__ __launch_bounds__(512, 4) void gemm_dual(
    const ushort* __restrict__ A1, const ushort* __restrict__ Bt1, float* __restrict__ C1,
    const ushort* __restrict__ A2, const ushort* __restrict__ Bt2, float* __restrict__ C2,
    const float* __restrict__ bias2)
{
    const int K = Ddim, N = Ddim;
    const int by = blockIdx.y;
    const ushort* A; const ushort* Bt; float* C; const float* bias; int m0;
    if (by < 16) { A = A1; Bt = Bt1; C = C1; bias = nullptr; m0 = by * GBM; }
    else         { A = A2; Bt = Bt2; C = C2; bias = bias2;  m0 = (by - 16) * GBM; }
    const int n0 = blockIdx.x * GBN;

    __shared__ __align__(16) ushort As[2][GBM * GBK];   // 2 x 8 KB
    __shared__ __align__(16) ushort Bs[2][GBN * GBK];   // 2 x 8 KB

    const int tid  = threadIdx.x;
    const int l    = tid & 63;
    const int wave = tid >> 6;          // 0..7

    const int wm = (wave >> 1) * 32;    // 0,32,64,96
    const int wn = (wave & 1) * 64;     // 0,64

    floatx4 acc[2][4];
    #pragma unroll
    for (int i = 0; i < 2; ++i)
        #pragma unroll
        for (int j = 0; j < 4; ++j)
            acc[i][j] = (floatx4){0.0f, 0.0f, 0.0f, 0.0f};

    const int lm = l & 15;
    const int lk = (l >> 4) * 8;

    const int crow = l >> 2;          // staging row within 16-row chunk
    const int ccol = (l & 3) * 8;     // staging k (ushort)

    const ushort* aSrc = A  + (size_t)(m0 + wave * 16 + crow) * K + ccol;   // all 8 waves
    const ushort* bSrc = Bt + (size_t)(n0 + wave * 16 + crow) * K + ccol;   // all 8 waves
    const int aOff = (wave * 16) * GBK;        // + lane*16B implicit in gload_lds
    const int bOff = (wave * 16) * GBK;

    const int NK = K / GBK;   // 32

    // prologue: tile 0 -> buf 0
    GLOAD_LDS16(aSrc, &As[0][aOff]);
    GLOAD_LDS16(bSrc, &Bs[0][bOff]);

    for (int i = 0; i < NK; ++i) {
        const int cur = i & 1;
        if (i + 1 < NK) {
            const int kn = (i + 1) * GBK;
            const int nxt = cur ^ 1;
            GLOAD_LDS16(aSrc + kn, &As[nxt][aOff]);
            GLOAD_LDS16(bSrc + kn, &Bs[nxt][bOff]);
            WAIT_VMCNT(2);     // cur tile's A+B retired; next tile's 2 in flight
        } else {
            WAIT_VMCNT(0);
        }
        __builtin_amdgcn_s_barrier();   // tile i visible to all waves

        short8 af0 = *(const short8*)&As[cur][(wm +  0 + lm) * GBK + lk];
        short8 af1 = *(const short8*)&As[cur][(wm + 16 + lm) * GBK + lk];
        short8 bf0 = *(const short8*)&Bs[cur][(wn +  0 + lm) * GBK + lk];
        short8 bf1 = *(const short8*)&Bs[cur][(wn + 16 + lm) * GBK + lk];
        short8 bf2 = *(const short8*)&Bs[cur][(wn + 32 + lm) * GBK + lk];
        short8 bf3 = *(const short8*)&Bs[cur][(wn + 48 + lm) * GBK + lk];
        acc[0][0] = __builtin_amdgcn_mfma_f32_16x16x32_bf16(af0, bf0, acc[0][0], 0, 0, 0);
        acc[0][1] = __builtin_amdgcn_mfma_f32_16x16x32_bf16(af0, bf1, acc[0][1], 0, 0, 0);
        acc[0][2] = __builtin_amdgcn_mfma_f32_16x16x32_bf16(af0, bf2, acc[0][2], 0, 0, 0);
        acc[0][3] = __builtin_amdgcn_mfma_f32_16x16x32_bf16(af0, bf3, acc[0][3], 0, 0, 0);
        acc[1][0] = __builtin_amdgcn_mfma_f32_16x16x32_bf16(af1, bf0, acc[1][0], 0, 0, 0);
        acc[1][1] = __builtin_amdgcn_mfma_f32_16x16x32_bf16(af1, bf1, acc[1][1], 0, 0, 0);
        acc[1][2] = __builtin_amdgcn_mfma_f32_16x16x32_bf16(af1, bf2, acc[1][2], 0, 0, 0);
        acc[1][3] = __builtin_amdgcn_mfma_f32_16x16x32_bf16(af1, bf3, acc[1][3], 0, 0, 0);

        __builtin_amdgcn_s_barrier();   // all readers of buf[cur] done
    }

    const int rowq = (l >> 4) * 4;
    #pragma unroll
    for (int im = 0; im < 2; ++im) {
        #pragma unroll
        for (int in_ = 0; in_ < 4; ++in_) {
            const int col = n0 + wn + in_ * 16 + lm;
            float badd = (bias != nullptr) ? bias[col] : 0.0f;
            #pragma unroll
            for (int r = 0; r < 4; ++r) {
                const int row = m0 + wm + im * 16 + rowq + r;
                // exp2-transformed projection factor (see header comment)
                C[(size_t)row * N + col] = fexp2((acc[im][in_][r] + badd) * TANH_SCALE);
            }
        }
    }
}

// ---------------------------------------------------------------------------
// attn v8: NF=2 + pair-rcp phase 1.
// Phase-1: w1/q1 + w2/q2 = (w1*q2 + w2*q1) / (q1*q2), qi = fmaf(tv,fv,1) > 1
// (both factors are positive exp2 outputs). Exact algebra; ONE rcp per TWO
// elements: 3 VALU + 0.5 trans per element (was 2 VALU + 1 trans). Trans-pipe
// floor 3.4 us -> 1.7 us; VALU 2.6 us becomes the cap.
// ---------------------------------------------------------------------------
__global__ __launch_bounds__(256, 4) void attn_fused(
    const float* __restrict__ feat,   // [B,F,D] raw
    const float* __restrict__ txt,    // [B,T,D] raw
    const int*   __restrict__ qmask,  // [B,T]
    const float* __restrict__ fp_s,   // [B*F,D]  exp2(c*feat_proj)
    const float* __restrict__ tp_s,   // [B*T,D]  exp2(c*(txt_proj+b))
    const float* __restrict__ wvec,   // [D]
    const float* __restrict__ Wcw,    // [D]
    const float* __restrict__ bcw,    // [1]
    const float* __restrict__ Wcb,    // [D]
    const float* __restrict__ bcb,    // [1]
    float* __restrict__ out)          // [B,F,D]
{
    const int blk  = blockIdx.x;          // 0..1023
    const int f0   = blk * 2;
    const int b    = f0 >> 8;
    const int tid  = threadIdx.x;
    const int lane = tid & 63;
    const int wave = tid >> 6;

    __shared__ float part[2][Tdim][68];   // stride 68: 2-way banks (free)
    __shared__ float srho[2][Tdim];
    __shared__ float satt[2][Tdim];
    __shared__ float sred[4][4];

    float4 wv[4], fva[4], fvb[4];
    const float* fr0 = fp_s + (size_t)f0 * Ddim;
    const float* fr1 = fr0 + Ddim;
    #pragma unroll
    for (int it = 0; it < 4; ++it) {
        const int d = lane * 4 + it * 256;
        wv[it]  = *(const float4*)&wvec[d];
        fva[it] = *(const float4*)&fr0[d];
        fvb[it] = *(const float4*)&fr1[d];
    }
    float sumw = 0.0f;
    #pragma unroll
    for (int it = 0; it < 4; ++it)
        sumw += wv[it].x + wv[it].y + wv[it].z + wv[it].w;
    #pragma unroll
    for (int off = 32; off; off >>= 1) sumw += __shfl_xor(sumw, off, 64);

    // ---- phase 1: partial logits, register double-buffered tp loads ----
    const float* tpb = tp_s + (size_t)b * Tdim * Ddim;
    float s0[8], s1[8];
    float4 cur[4], nxt[4];
    {
        const float* tr = tpb + (size_t)(wave * 8) * Ddim;
        #pragma unroll
        for (int it = 0; it < 4; ++it)
            cur[it] = *(const float4*)&tr[lane * 4 + it * 256];
    }
    #pragma unroll
    for (int tt = 0; tt < 8; ++tt) {
        if (tt < 7) {
            const float* trn = tpb + (size_t)(wave * 8 + tt + 1) * Ddim;
            #pragma unroll
            for (int it = 0; it < 4; ++it)
                nxt[it] = *(const float4*)&trn[lane * 4 + it * 256];
        }
        float a0 = 0.0f, b0 = 0.0f, a1 = 0.0f, b1 = 0.0f;
        #pragma unroll
        for (int it = 0; it < 4; ++it) {
            const float4 tv  = cur[it];
            const float4 wvi = wv[it];
            float q1, q2, num;
            // row a: pairs (x,y) and (z,w)
            q1 = fmaf(tv.x, fva[it].x, 1.0f);
            q2 = fmaf(tv.y, fva[it].y, 1.0f);
            num = fmaf(wvi.x, q2, wvi.y * q1);
            a0 = fmaf(num, frcp(q1 * q2), a0);
            q1 = fmaf(tv.z, fva[it].z, 1.0f);
            q2 = fmaf(tv.w, fva[it].w, 1.0f);
            num = fmaf(wvi.z, q2, wvi.w * q1);
            b0 = fmaf(num, frcp(q1 * q2), b0);
            // row b: pairs (x,y) and (z,w)
            q1 = fmaf(tv.x, fvb[it].x, 1.0f);
            q2 = fmaf(tv.y, fvb[it].y, 1.0f);
            num = fmaf(wvi.x, q2, wvi.y * q1);
            a1 = fmaf(num, frcp(q1 * q2), a1);
            q1 = fmaf(tv.z, fvb[it].z, 1.0f);
            q2 = fmaf(tv.w, fvb[it].w, 1.0f);
            num = fmaf(wvi.z, q2, wvi.w * q1);
            b1 = fmaf(num, frcp(q1 * q2), b1);
        }
        s0[tt] = a0 + b0;
        s1[tt] = a1 + b1;
        #pragma unroll
        for (int it = 0; it < 4; ++it) cur[it] = nxt[it];
    }
    #pragma unroll
    for (int tt = 0; tt < 8; ++tt) {
        part[0][wave * 8 + tt][lane] = s0[tt];
        part[1][wave * 8 + tt][lane] = s1[tt];
    }
    __syncthreads();

    // ---- deferred reduction: 4 threads per (f,t) pair ----
    {
        const int pair = tid >> 2, q = tid & 3;
        const int f = pair >> 5, t = pair & 31;
        const float* src = &part[f][t][q * 16];
        float4 v0 = *(const float4*)(src);
        float4 v1 = *(const float4*)(src + 4);
        float4 v2 = *(const float4*)(src + 8);
        float4 v3 = *(const float4*)(src + 12);
        float sum = ((v0.x + v0.y) + (v0.z + v0.w))
                  + ((v1.x + v1.y) + (v1.z + v1.w))
                  + ((v2.x + v2.y) + (v2.z + v2.w))
                  + ((v3.x + v3.y) + (v3.z + v3.w));
        sum += __shfl_xor(sum, 1, 64);
        sum += __shfl_xor(sum, 2, 64);
        if (q == 0) srho[f][t] = sum;
    }
    __syncthreads();

    // ---- softmax: wave 0, 32 lanes per f-row ----
    if (wave == 0) {
        const int f = lane >> 5, t = lane & 31;
        const float q = (float)qmask[b * Tdim + t];
        float L = sumw - 2.0f * srho[f][t] + (1.0f - q) * NEGV;
        float m = L;
        #pragma unroll
        for (int off = 16; off; off >>= 1) m = fmaxf(m, __shfl_xor(m, off, 64));
        float e = fexp2((L - m) * LOG2E);
        float ssum = e;
        #pragma unroll
        for (int off = 16; off; off >>= 1) ssum += __shfl_xor(ssum, off, 64);
        satt[f][t] = e * frcp(ssum);
    }
    __syncthreads();

    // ---- phase 2: txt_h for both f rows; thread owns d0 = tid*4 ----
    const float* txtb = txt + (size_t)b * Tdim * Ddim;
    const int d0 = tid * 4;
    float4 th0 = {0,0,0,0}, th1 = {0,0,0,0};
    #pragma unroll 8
    for (int t = 0; t < Tdim; ++t) {
        float4 tv = *(const float4*)&txtb[(size_t)t * Ddim + d0];
        const float a0 = satt[0][t], a1 = satt[1][t];
        th0.x = fmaf(a0, tv.x, th0.x); th0.y = fmaf(a0, tv.y, th0.y);
        th0.z = fmaf(a0, tv.z, th0.z); th0.w = fmaf(a0, tv.w, th0.w);
        th1.x = fmaf(a1, tv.x, th1.x); th1.y = fmaf(a1, tv.y, th1.y);
        th1.z = fmaf(a1, tv.z, th1.z); th1.w = fmaf(a1, tv.w, th1.w);
    }

    float4 wcw = *(const float4*)&Wcw[d0];
    float4 wcb = *(const float4*)&Wcb[d0];
    float p00 = th0.x*wcw.x + th0.y*wcw.y + th0.z*wcw.z + th0.w*wcw.w;
    float p01 = th0.x*wcb.x + th0.y*wcb.y + th0.z*wcb.z + th0.w*wcb.w;
    float p10 = th1.x*wcw.x + th1.y*wcw.y + th1.z*wcw.z + th1.w*wcw.w;
    float p11 = th1.x*wcb.x + th1.y*wcb.y + th1.z*wcb.z + th1.w*wcb.w;
    #pragma unroll
    for (int off = 32; off; off >>= 1) {
        p00 += __shfl_xor(p00, off, 64);
        p01 += __shfl_xor(p01, off, 64);
        p10 += __shfl_xor(p10, off, 64);
        p11 += __shfl_xor(p11, off, 64);
    }
    if (lane == 0) {
        sred[wave][0] = p00; sred[wave][1] = p01;
        sred[wave][2] = p10; sred[wave][3] = p11;
    }
    __syncthreads();
    const float c00 = sred[0][0] + sred[1][0] + sred[2][0] + sred[3][0];
    const float c01 = sred[0][1] + sred[1][1] + sred[2][1] + sred[3][1];
    const float c10 = sred[0][2] + sred[1][2] + sred[2][2] + sred[3][2];
    const float c11 = sred[0][3] + sred[1][3] + sred[2][3] + sred[3][3];
    const float ws0 = fast_tanh(c00 + bcw[0]);
    const float bs0 = fast_tanh(c01 + bcb[0]);
    const float ws1 = fast_tanh(c10 + bcw[0]);
    const float bs1 = fast_tanh(c11 + bcb[0]);

    const float* ft0 = feat + (size_t)f0 * Ddim;
    float4 v0 = *(const float4*)&ft0[d0];
    float4 v1 = *(const float4*)&ft0[Ddim + d0];
    float4 o0, o1;
    o0.x = fmaf(ws0, v0.x, bs0); o0.y = fmaf(ws0, v0.y, bs0);
    o0.z = fmaf(ws0, v0.z, bs0); o0.w = fmaf(ws0, v0.w, bs0);
    o1.x = fmaf(ws1, v1.x, bs1); o1.y = fmaf(ws1, v1.y, bs1);
    o1.z = fmaf(ws1, v1.z, bs1); o1.w = fmaf(ws1, v1.w, bs1);
    *(float4*)&out[(size_t)f0 * Ddim + d0] = o0;
    *(float4*)&out[(size_t)f0 * Ddim + Ddim + d0] = o1;
}

// ---------------------------------------------------------------------------
extern "C" void kernel_launch(void* const* d_in, const int* in_sizes, int n_in,
                              void* d_out, int out_size, void* d_ws, size_t ws_size,
                              hipStream_t stream) {
    const float* features = (const float*)d_in[0];   // [B,F,D]
    const float* textual  = (const float*)d_in[2];   // [B,T,D]
    const int*   q_masks  = (const int*)d_in[3];     // [B,T]
    const float* Ws       = (const float*)d_in[4];   // [D,D]
    const float* W        = (const float*)d_in[5];   // [D,D]
    const float* wvec     = (const float*)d_in[6];   // [D,1]
    const float* bvec     = (const float*)d_in[7];   // [1,D]
    const float* Wcw      = (const float*)d_in[8];   // [1,D]
    const float* bcw      = (const float*)d_in[9];   // [1]
    const float* Wcb      = (const float*)d_in[10];  // [1,D]
    const float* bcb      = (const float*)d_in[11];  // [1]
    float* out = (float*)d_out;

    float*  fp_ws = (float*)d_ws;                          // 2048*1024 f32 (exp2-transformed)
    float*  tp_ws = fp_ws + (size_t)Bdim * Fdim * Ddim;    // 256*1024 f32 (exp2-transformed)
    ushort* featB = (ushort*)(tp_ws + (size_t)Bdim * Tdim * Ddim);
    ushort* txtB  = featB + (size_t)Bdim * Fdim * Ddim;
    ushort* WtB   = txtB + (size_t)Bdim * Tdim * Ddim;
    ushort* WstB  = WtB + (size_t)Ddim * Ddim;

    // 1. merged prep: cast activations + transpose/cast weights
    prep<<<Bdim * Fdim + Bdim * Tdim + 2048, 256, 0, stream>>>(
        features, textual, W, Ws, featB, txtB, WtB, WstB);
    // 2. both projections, one MFMA dispatch (144 blocks <= 256 CUs)
    gemm_dual<<<dim3(Ddim / GBN, 18), 512, 0, stream>>>(
        featB, WtB, fp_ws, txtB, WstB, tp_ws, bvec);
    // 3. fused attention + conditioning (NF=2, pair-rcp phase 1)
    attn_fused<<<(Bdim * Fdim) / 2, 256, 0, stream>>>(
        features, textual, q_masks, fp_ws, tp_ws,
        wvec, Wcw, bcw, Wcb, bcb, out);
}